// Round 1
// baseline (2693.214 us; speedup 1.0000x reference)
//
#include <hip/hip_runtime.h>
#include <math.h>

#define NN 50000
#define EE 800000
#define HH 128

__device__ __forceinline__ float sigf(float x)  { return 1.0f/(1.0f+__expf(-x)); }
__device__ __forceinline__ float siluf(float x) { return x/(1.0f+__expf(-x)); }

// ---------------- Kernel A: h = node_feat @ Wi + bi ----------------
__global__ __launch_bounds__(256) void k_linin(
    const float* __restrict__ nf, const float* __restrict__ Wi,
    const float* __restrict__ bi, float* __restrict__ h) {
  __shared__ __align__(16) float Wl[128*128];
  __shared__ __align__(16) float xl[16*128];
  const int t = threadIdx.x;
  for (int i = t*4; i < 128*128; i += 1024)
    *(float4*)&Wl[i] = *(const float4*)&Wi[i];
  const int c0 = (t&31)*4, rg = t>>5;
  const float4 bv = *(const float4*)&bi[c0];
  for (int tile = blockIdx.x; tile < NN/16; tile += gridDim.x) {
    const int r0 = tile*16;
    __syncthreads();
    for (int i = t*4; i < 16*128; i += 1024)
      *(float4*)&xl[i] = *(const float4*)&nf[(size_t)r0*128 + i];
    __syncthreads();
    float a0x=0,a0y=0,a0z=0,a0w=0,a1x=0,a1y=0,a1z=0,a1w=0;
    #pragma unroll 4
    for (int k = 0; k < 128; ++k) {
      const float4 w = *(float4*)&Wl[k*128 + c0];
      const float x0 = xl[(rg*2)*128 + k];
      const float x1 = xl[(rg*2+1)*128 + k];
      a0x+=x0*w.x; a0y+=x0*w.y; a0z+=x0*w.z; a0w+=x0*w.w;
      a1x+=x1*w.x; a1y+=x1*w.y; a1z+=x1*w.z; a1w+=x1*w.w;
    }
    *(float4*)&h[((size_t)r0+rg*2)*128 + c0] =
        make_float4(a0x+bv.x, a0y+bv.y, a0z+bv.z, a0w+bv.w);
    *(float4*)&h[((size_t)r0+rg*2+1)*128 + c0] =
        make_float4(a1x+bv.x, a1y+bv.y, a1z+bv.z, a1w+bv.w);
  }
}

// ---------------- Kernel B: per-edge message MLP + scatter ----------------
__global__ __launch_bounds__(256) void k_edge(
    const int* __restrict__ ei, const float* __restrict__ pos,
    const float* __restrict__ h,
    const float* __restrict__ W1, const float* __restrict__ b1,
    const float* __restrict__ W2, const float* __restrict__ b2,
    float* __restrict__ agg, float* __restrict__ gvsum) {
  __shared__ __align__(16) float W1l[136*128];   // 69632 B
  __shared__ __align__(16) float W2l[128*128];   // 65536 B
  __shared__ __align__(16) float xl[32*136];     // 17408 B (reused as m1[32][128])
  __shared__ float dirl[32][3];
  __shared__ float gatel[32];
  __shared__ int   dstl[32];
  const int t = threadIdx.x;
  for (int i = t*4; i < 136*128; i += 1024)
    *(float4*)&W1l[i] = *(const float4*)&W1[i];
  for (int i = t*4; i < 128*128; i += 1024)
    *(float4*)&W2l[i] = *(const float4*)&W2[i];
  const int c0 = (t&31)*4, eg = t>>5;
  const int tg = t&31, grp = t>>5;
  const float4 b1v = *(const float4*)&b1[c0];
  const float4 b2v = *(const float4*)&b2[c0];
  for (int tile = blockIdx.x; tile < EE/32; tile += gridDim.x) {
    __syncthreads();
    // ---- stage 32 edges: gathered h_src + rbf, geometry, gate ----
    #pragma unroll
    for (int p = 0; p < 4; ++p) {
      const int le = p*8 + grp;
      const int e  = tile*32 + le;
      const int s  = ei[e];
      const int d  = ei[EE + e];
      float a = 0.f;
      #pragma unroll
      for (int j = 0; j < 4; ++j) {
        const int k = tg + j*32;
        const float v = h[(size_t)s*128 + k];
        xl[le*136 + k] = v;
        a += v;
      }
      #pragma unroll
      for (int m = 16; m > 0; m >>= 1) a += __shfl_xor(a, m, 32);
      if (tg == 0) {
        dstl[le] = d;
        const float rx = pos[d*3+0]-pos[s*3+0];
        const float ry = pos[d*3+1]-pos[s*3+1];
        const float rz = pos[d*3+2]-pos[s*3+2];
        const float dij = sqrtf(rx*rx+ry*ry+rz*rz);
        const float inv = 1.0f/(dij + 1e-8f);
        dirl[le][0]=rx*inv; dirl[le][1]=ry*inv; dirl[le][2]=rz*inv;
        gatel[le] = sigf(a);
        #pragma unroll
        for (int q = 0; q < 8; ++q) {
          const float dc = dij - (float)q * (8.0f/7.0f);  // linspace(0,8,8), gamma=0.5
          xl[le*136 + 128 + q] = __expf(-0.5f*dc*dc);
        }
      }
    }
    __syncthreads();
    // ---- g_vec partial: sum(gate * dir) over tile ----
    if (t < 32) {
      const float g = gatel[t];
      float vx = g*dirl[t][0], vy = g*dirl[t][1], vz = g*dirl[t][2];
      #pragma unroll
      for (int m = 16; m > 0; m >>= 1) {
        vx += __shfl_xor(vx, m, 32);
        vy += __shfl_xor(vy, m, 32);
        vz += __shfl_xor(vz, m, 32);
      }
      if (t == 0) { atomicAdd(&gvsum[0],vx); atomicAdd(&gvsum[1],vy); atomicAdd(&gvsum[2],vz); }
    }
    // ---- m1 = x @ W1 : each thread 4 edges x 4 cols ----
    float acc[4][4] = {};
    #pragma unroll 2
    for (int k = 0; k < 136; ++k) {
      const float4 w = *(float4*)&W1l[k*128 + c0];
      #pragma unroll
      for (int i = 0; i < 4; ++i) {
        const float x = xl[(eg*4+i)*136 + k];
        acc[i][0]+=x*w.x; acc[i][1]+=x*w.y; acc[i][2]+=x*w.z; acc[i][3]+=x*w.w;
      }
    }
    __syncthreads();
    #pragma unroll
    for (int i = 0; i < 4; ++i) {
      float4 o;
      o.x = siluf(acc[i][0]+b1v.x);
      o.y = siluf(acc[i][1]+b1v.y);
      o.z = siluf(acc[i][2]+b1v.z);
      o.w = siluf(acc[i][3]+b1v.w);
      *(float4*)&xl[(eg*4+i)*128 + c0] = o;   // reuse xl as m1[32][128]
    }
    __syncthreads();
    // ---- m = silu(m1) @ W2 ----
    float ac2[4][4] = {};
    #pragma unroll 2
    for (int k = 0; k < 128; ++k) {
      const float4 w = *(float4*)&W2l[k*128 + c0];
      #pragma unroll
      for (int i = 0; i < 4; ++i) {
        const float x = xl[(eg*4+i)*128 + k];
        ac2[i][0]+=x*w.x; ac2[i][1]+=x*w.y; ac2[i][2]+=x*w.z; ac2[i][3]+=x*w.w;
      }
    }
    // ---- scatter-add into agg[dst] ----
    #pragma unroll
    for (int i = 0; i < 4; ++i) {
      const int d = dstl[eg*4+i];
      float* p4 = &agg[(size_t)d*128 + c0];
      atomicAdd(p4+0, ac2[i][0]+b2v.x);
      atomicAdd(p4+1, ac2[i][1]+b2v.y);
      atomicAdd(p4+2, ac2[i][2]+b2v.z);
      atomicAdd(p4+3, ac2[i][3]+b2v.w);
    }
  }
}

// ---------------- Kernel C: update MLP + LayerNorm + g_P partials ----------------
__global__ __launch_bounds__(256) void k_upd(
    const float* h /*aliases hn*/, const float* __restrict__ agg,
    const float* __restrict__ U1, const float* __restrict__ u1,
    const float* __restrict__ U2, const float* __restrict__ u2,
    const float* __restrict__ lg, const float* __restrict__ lb,
    float* hn, float* __restrict__ gsum) {
  __shared__ __align__(16) float U1l[256*128];  // 131072 B
  __shared__ __align__(16) float xl[16*256];    // 16384
  __shared__ __align__(16) float t1l[16*128];   // 8192
  __shared__ __align__(16) float cred[4*128];   // 2048  -> 157696 total
  const int t = threadIdx.x;
  for (int i = t*4; i < 256*128; i += 1024)
    *(float4*)&U1l[i] = *(const float4*)&U1[i];
  const int c0 = (t&31)*4, rg = t>>5;
  const float4 u1v = *(const float4*)&u1[c0];
  const float4 u2v = *(const float4*)&u2[c0];
  const float4 gv4 = *(const float4*)&lg[c0];
  const float4 bv4 = *(const float4*)&lb[c0];
  float pc0=0, pc1=0, pc2=0, pc3=0;
  for (int tile = blockIdx.x; tile < NN/16; tile += gridDim.x) {
    const int r0 = tile*16;
    __syncthreads();
    for (int i = t*4; i < 16*256; i += 1024) {
      const int r = i >> 8, k = i & 255;
      const float4 v = (k < 128)
          ? *(const float4*)&h  [((size_t)r0+r)*128 + k]
          : *(const float4*)&agg[((size_t)r0+r)*128 + (k-128)];
      *(float4*)&xl[i] = v;
    }
    __syncthreads();
    float a0x=0,a0y=0,a0z=0,a0w=0,a1x=0,a1y=0,a1z=0,a1w=0;
    #pragma unroll 2
    for (int k = 0; k < 256; ++k) {
      const float4 w = *(float4*)&U1l[k*128 + c0];
      const float x0 = xl[(rg*2)*256 + k];
      const float x1 = xl[(rg*2+1)*256 + k];
      a0x+=x0*w.x; a0y+=x0*w.y; a0z+=x0*w.z; a0w+=x0*w.w;
      a1x+=x1*w.x; a1y+=x1*w.y; a1z+=x1*w.z; a1w+=x1*w.w;
    }
    *(float4*)&t1l[(rg*2)*128 + c0] = make_float4(
        siluf(a0x+u1v.x), siluf(a0y+u1v.y), siluf(a0z+u1v.z), siluf(a0w+u1v.w));
    *(float4*)&t1l[(rg*2+1)*128 + c0] = make_float4(
        siluf(a1x+u1v.x), siluf(a1y+u1v.y), siluf(a1z+u1v.z), siluf(a1w+u1v.w));
    __syncthreads();
    float b0x=0,b0y=0,b0z=0,b0w=0,b1x=0,b1y=0,b1z=0,b1w=0;
    #pragma unroll 2
    for (int k = 0; k < 128; ++k) {
      const float4 w = *(const float4*)&U2[k*128 + c0];   // global, cached
      const float x0 = t1l[(rg*2)*128 + k];
      const float x1 = t1l[(rg*2+1)*128 + k];
      b0x+=x0*w.x; b0y+=x0*w.y; b0z+=x0*w.z; b0w+=x0*w.w;
      b1x+=x1*w.x; b1y+=x1*w.y; b1z+=x1*w.z; b1w+=x1*w.w;
    }
    const float v00=b0x+u2v.x, v01=b0y+u2v.y, v02=b0z+u2v.z, v03=b0w+u2v.w;
    const float v10=b1x+u2v.x, v11=b1y+u2v.y, v12=b1z+u2v.z, v13=b1w+u2v.w;
    float s0 = v00+v01+v02+v03, q0 = v00*v00+v01*v01+v02*v02+v03*v03;
    float s1 = v10+v11+v12+v13, q1 = v10*v10+v11*v11+v12*v12+v13*v13;
    #pragma unroll
    for (int m = 16; m > 0; m >>= 1) {
      s0 += __shfl_xor(s0,m,32); q0 += __shfl_xor(q0,m,32);
      s1 += __shfl_xor(s1,m,32); q1 += __shfl_xor(q1,m,32);
    }
    const float mu0 = s0*(1.f/128.f), var0 = q0*(1.f/128.f)-mu0*mu0;
    const float mu1 = s1*(1.f/128.f), var1 = q1*(1.f/128.f)-mu1*mu1;
    const float rs0 = rsqrtf(var0+1e-5f), rs1 = rsqrtf(var1+1e-5f);
    const float h00=(v00-mu0)*rs0*gv4.x+bv4.x, h01=(v01-mu0)*rs0*gv4.y+bv4.y;
    const float h02=(v02-mu0)*rs0*gv4.z+bv4.z, h03=(v03-mu0)*rs0*gv4.w+bv4.w;
    const float h10=(v10-mu1)*rs1*gv4.x+bv4.x, h11=(v11-mu1)*rs1*gv4.y+bv4.y;
    const float h12=(v12-mu1)*rs1*gv4.z+bv4.z, h13=(v13-mu1)*rs1*gv4.w+bv4.w;
    *(float4*)&hn[((size_t)r0+rg*2)*128 + c0]   = make_float4(h00,h01,h02,h03);
    *(float4*)&hn[((size_t)r0+rg*2+1)*128 + c0] = make_float4(h10,h11,h12,h13);
    pc0 += h00+h10; pc1 += h01+h11; pc2 += h02+h12; pc3 += h03+h13;
  }
  // column-sum partials -> gsum
  pc0 += __shfl_xor(pc0, 32, 64);
  pc1 += __shfl_xor(pc1, 32, 64);
  pc2 += __shfl_xor(pc2, 32, 64);
  pc3 += __shfl_xor(pc3, 32, 64);
  __syncthreads();
  if ((t & 32) == 0) {
    const int w = t >> 6;
    cred[w*128 + c0+0] = pc0; cred[w*128 + c0+1] = pc1;
    cred[w*128 + c0+2] = pc2; cred[w*128 + c0+3] = pc3;
  }
  __syncthreads();
  if (t < 128) {
    const float s = cred[t] + cred[128+t] + cred[256+t] + cred[384+t];
    atomicAdd(&gsum[t], s);
  }
}

// ---------------- Kernel D: finalize g_P, g_vec ----------------
__global__ void k_fin(const float* __restrict__ gsum, const float* __restrict__ gvsum,
                      float* __restrict__ gp, float* __restrict__ gvo) {
  const int t = threadIdx.x;
  if (t < 128) gp[t] = gsum[t] * (1.0f/NN);
  if (t == 0) {
    const float x = gvsum[0]*(1.0f/NN);
    const float y = gvsum[1]*(1.0f/NN);
    const float z = gvsum[2]*(1.0f/NN);
    const float n = sqrtf(x*x+y*y+z*z) + 1e-8f;
    gvo[0]=x/n; gvo[1]=y/n; gvo[2]=z/n;
  }
}

extern "C" void kernel_launch(void* const* d_in, const int* in_sizes, int n_in,
                              void* d_out, int out_size, void* d_ws, size_t ws_size,
                              hipStream_t stream) {
  const float* nf  = (const float*)d_in[0];
  const float* pos = (const float*)d_in[1];
  const int*   ei  = (const int*)d_in[2];
  const float* Wi  = (const float*)d_in[3];
  const float* bi  = (const float*)d_in[4];
  const float* W1  = (const float*)d_in[5];
  const float* b1  = (const float*)d_in[6];
  const float* W2  = (const float*)d_in[7];
  const float* b2  = (const float*)d_in[8];
  const float* U1  = (const float*)d_in[9];
  const float* u1  = (const float*)d_in[10];
  const float* U2  = (const float*)d_in[11];
  const float* u2  = (const float*)d_in[12];
  const float* lg  = (const float*)d_in[13];
  const float* lb  = (const float*)d_in[14];

  float* out = (float*)d_out;
  float* h   = out;                         // h lives in d_out, overwritten by hn
  float* gp  = out + (size_t)NN*HH;
  float* gv  = gp + HH;

  float* agg   = (float*)d_ws;              // N*128
  float* gsum  = agg + (size_t)NN*HH;       // 128
  float* gvsum = gsum + HH;                 // 3

  hipMemsetAsync(d_ws, 0, ((size_t)NN*HH + 131)*sizeof(float), stream);
  k_linin<<<1024, 256, 0, stream>>>(nf, Wi, bi, h);
  k_edge <<<512,  256, 0, stream>>>(ei, pos, h, W1, b1, W2, b2, agg, gvsum);
  k_upd  <<<512,  256, 0, stream>>>(h, agg, U1, u1, U2, u2, lg, lb, out, gsum);
  k_fin  <<<1,    128, 0, stream>>>(gsum, gvsum, gp, gv);
}

// Round 2
// 721.604 us; speedup vs baseline: 3.7323x; 3.7323x over previous
//
#include <hip/hip_runtime.h>
#include <math.h>

#define NN 50000
#define EE 800000
#define HH 128

typedef _Float16 f16;
typedef _Float16 f16x4 __attribute__((ext_vector_type(4)));
typedef _Float16 f16x8 __attribute__((ext_vector_type(8)));
typedef float f32x4 __attribute__((ext_vector_type(4)));

__device__ __forceinline__ float sigf(float x)  { return 1.0f/(1.0f+__expf(-x)); }
__device__ __forceinline__ float siluf(float x) { return x/(1.0f+__expf(-x)); }

// ---------------- Kernel A: h = node_feat @ Wi + bi ; hsum = rowsum(h) ----------------
__global__ __launch_bounds__(256) void k_linin(
    const float* __restrict__ nf, const float* __restrict__ Wi,
    const float* __restrict__ bi, float* __restrict__ h, float* __restrict__ hsum) {
  __shared__ __align__(16) float Wl[128*128];
  __shared__ __align__(16) float xl[16*128];
  const int t = threadIdx.x;
  for (int i = t*4; i < 128*128; i += 1024)
    *(float4*)&Wl[i] = *(const float4*)&Wi[i];
  const int c0 = (t&31)*4, rg = t>>5;
  const float4 bv = *(const float4*)&bi[c0];
  for (int tile = blockIdx.x; tile < NN/16; tile += gridDim.x) {
    const int r0 = tile*16;
    __syncthreads();
    for (int i = t*4; i < 16*128; i += 1024)
      *(float4*)&xl[i] = *(const float4*)&nf[(size_t)r0*128 + i];
    __syncthreads();
    float a0x=0,a0y=0,a0z=0,a0w=0,a1x=0,a1y=0,a1z=0,a1w=0;
    #pragma unroll 4
    for (int k = 0; k < 128; ++k) {
      const float4 w = *(float4*)&Wl[k*128 + c0];
      const float x0 = xl[(rg*2)*128 + k];
      const float x1 = xl[(rg*2+1)*128 + k];
      a0x+=x0*w.x; a0y+=x0*w.y; a0z+=x0*w.z; a0w+=x0*w.w;
      a1x+=x1*w.x; a1y+=x1*w.y; a1z+=x1*w.z; a1w+=x1*w.w;
    }
    const float h00=a0x+bv.x, h01=a0y+bv.y, h02=a0z+bv.z, h03=a0w+bv.w;
    const float h10=a1x+bv.x, h11=a1y+bv.y, h12=a1z+bv.z, h13=a1w+bv.w;
    *(float4*)&h[((size_t)r0+rg*2)*128 + c0]   = make_float4(h00,h01,h02,h03);
    *(float4*)&h[((size_t)r0+rg*2+1)*128 + c0] = make_float4(h10,h11,h12,h13);
    float s0 = h00+h01+h02+h03, s1 = h10+h11+h12+h13;
    #pragma unroll
    for (int m = 16; m > 0; m >>= 1) {
      s0 += __shfl_xor(s0, m, 32);
      s1 += __shfl_xor(s1, m, 32);
    }
    if ((t&31) == 0) {
      hsum[r0+rg*2]   = s0;
      hsum[r0+rg*2+1] = s1;
    }
  }
}

// ---------------- Sort kernels: count / scan / scatter ----------------
__global__ void k_count(const int* __restrict__ ei, int* __restrict__ cnt) {
  const int e = blockIdx.x*256 + threadIdx.x;
  if (e < EE) atomicAdd(&cnt[ei[EE+e]], 1);
}

__global__ __launch_bounds__(1024) void k_scan(const int* __restrict__ cnt,
                                               int* __restrict__ off, int* __restrict__ cur) {
  __shared__ int part[1024];
  const int t = threadIdx.x;
  const int CH = 49;  // 49*1024 = 50176 >= 50000
  const int base = t*CH;
  int s = 0;
  for (int i = 0; i < CH; ++i) {
    const int idx = base+i;
    s += (idx < NN) ? cnt[idx] : 0;
  }
  part[t] = s;
  __syncthreads();
  for (int d = 1; d < 1024; d <<= 1) {
    int u = (t >= d) ? part[t-d] : 0;
    __syncthreads();
    part[t] += u;
    __syncthreads();
  }
  int run = part[t] - s;  // exclusive prefix of this thread's chunk
  for (int i = 0; i < CH; ++i) {
    const int idx = base+i;
    if (idx < NN) { off[idx] = run; cur[idx] = run; run += cnt[idx]; }
  }
}

__global__ void k_scatter(const int* __restrict__ ei, int* __restrict__ cur,
                          int* __restrict__ sSrc, int* __restrict__ sDst) {
  const int e = blockIdx.x*256 + threadIdx.x;
  if (e < EE) {
    const int d = ei[EE+e];
    const int p = atomicAdd(&cur[d], 1);
    sSrc[p] = ei[e];
    sDst[p] = d;
  }
}

// ---------------- Kernel B: MFMA edge MLP + segmented scatter ----------------
// 256 thr = 4 waves; each wave owns a 32-col slice of the 128 output cols.
// Tile = 64 dst-sorted edges. X[64][160] f16 in LDS (K=136 padded to 160).
// W1,W2 fragments live in registers per wave.
__global__ __launch_bounds__(256) void k_edge(
    const int* __restrict__ sSrc, const int* __restrict__ sDst,
    const float* __restrict__ pos, const float* __restrict__ h,
    const float* __restrict__ hsum,
    const float* __restrict__ W1, const float* __restrict__ b1,
    const float* __restrict__ W2, const float* __restrict__ b2,
    float* __restrict__ agg, float* __restrict__ gvsum) {
  __shared__ __align__(16) unsigned char smem[64*168*2 + 64*136*2];  // 38912 B
  __shared__ int   sdst[64];
  __shared__ float vred[64*3];
  f16*   xl   = (f16*)smem;                    // [64][168] (row uses [0,160))
  f16*   m1l  = (f16*)(smem + 64*168*2);       // [64][136] (row uses [0,128))
  float* Mlds = (float*)smem;                  // [64][132] overlay (33792 B)

  const int t = threadIdx.x;
  const int w = t >> 6, l = t & 63;
  const int lr = l & 15;           // row (A) / col (B,C) within fragment
  const int lg = l >> 4;           // k-subgroup
  const int le = t >> 2, q = t & 3;

  // ---- load weight fragments into registers (once) ----
  f16x8 W1f[5][2], W2f[4][2];
  #pragma unroll
  for (int ks = 0; ks < 5; ++ks)
    #pragma unroll
    for (int nf = 0; nf < 2; ++nf) {
      f16x8 v;
      #pragma unroll
      for (int j = 0; j < 8; ++j) {
        const int k = ks*32 + lg*8 + j;
        const int c = w*32 + nf*16 + lr;
        v[j] = (k < 136) ? (f16)W1[k*128 + c] : (f16)0.f;
      }
      W1f[ks][nf] = v;
    }
  #pragma unroll
  for (int ks = 0; ks < 4; ++ks)
    #pragma unroll
    for (int nf = 0; nf < 2; ++nf) {
      f16x8 v;
      #pragma unroll
      for (int j = 0; j < 8; ++j) {
        const int k = ks*32 + lg*8 + j;
        const int c = w*32 + nf*16 + lr;
        v[j] = (f16)W2[k*128 + c];
      }
      W2f[ks][nf] = v;
    }
  float b1v[2], b2v[2];
  #pragma unroll
  for (int nf = 0; nf < 2; ++nf) {
    b1v[nf] = b1[w*32 + nf*16 + lr];
    b2v[nf] = b2[w*32 + nf*16 + lr];
  }

  float vxa = 0.f, vya = 0.f, vza = 0.f;

  for (int tile = blockIdx.x; tile < EE/64; tile += gridDim.x) {
    const int e0 = tile*64;
    __syncthreads();  // previous tile's reduce done before we clobber xl
    // ---- stage 64 edges: gather h[src] -> f16, rbf, geometry, gate ----
    {
      const int s = sSrc[e0 + le];
      #pragma unroll
      for (int i = 0; i < 8; ++i) {
        const float4 v4 = *(const float4*)&h[(size_t)s*128 + q*32 + i*4];
        f16x4 o = { (f16)v4.x, (f16)v4.y, (f16)v4.z, (f16)v4.w };
        *(f16x4*)&xl[le*168 + q*32 + i*4] = o;
      }
      if (q == 0) {
        const int d = sDst[e0 + le];
        sdst[le] = d;
        const float rx = pos[d*3+0]-pos[s*3+0];
        const float ry = pos[d*3+1]-pos[s*3+1];
        const float rz = pos[d*3+2]-pos[s*3+2];
        const float dij = sqrtf(rx*rx+ry*ry+rz*rz);
        const float inv = 1.0f/(dij + 1e-8f);
        const float g = sigf(hsum[s]);
        vxa += g*rx*inv; vya += g*ry*inv; vza += g*rz*inv;
        #pragma unroll
        for (int qq = 0; qq < 8; ++qq) {
          const float dc = dij - (float)qq * (8.0f/7.0f);
          xl[le*168 + 128 + qq] = (f16)__expf(-0.5f*dc*dc);
        }
        f16x8 z;
        #pragma unroll
        for (int j = 0; j < 8; ++j) z[j] = (f16)0.f;
        *(f16x8*)&xl[le*168 + 136] = z;
        *(f16x8*)&xl[le*168 + 144] = z;
        *(f16x8*)&xl[le*168 + 152] = z;
      }
    }
    __syncthreads();
    // ---- GEMM1: m1 = X @ W1, K=160 ----
    f32x4 acc[4][2];
    #pragma unroll
    for (int mf = 0; mf < 4; ++mf)
      #pragma unroll
      for (int nf = 0; nf < 2; ++nf)
        acc[mf][nf] = (f32x4){0.f,0.f,0.f,0.f};
    #pragma unroll
    for (int ks = 0; ks < 5; ++ks)
      #pragma unroll
      for (int mf = 0; mf < 4; ++mf) {
        const f16x8 A = *(f16x8*)&xl[(mf*16 + lr)*168 + ks*32 + lg*8];
        acc[mf][0] = __builtin_amdgcn_mfma_f32_16x16x32_f16(A, W1f[ks][0], acc[mf][0], 0, 0, 0);
        acc[mf][1] = __builtin_amdgcn_mfma_f32_16x16x32_f16(A, W1f[ks][1], acc[mf][1], 0, 0, 0);
      }
    // ---- m1 = silu(acc+b1) -> LDS f16 ----
    #pragma unroll
    for (int mf = 0; mf < 4; ++mf)
      #pragma unroll
      for (int nf = 0; nf < 2; ++nf)
        #pragma unroll
        for (int j = 0; j < 4; ++j) {
          const float v = siluf(acc[mf][nf][j] + b1v[nf]);
          m1l[(mf*16 + lg*4 + j)*136 + (w*32 + nf*16 + lr)] = (f16)v;
        }
    __syncthreads();
    // ---- GEMM2: M = m1 @ W2, K=128 ----
    #pragma unroll
    for (int mf = 0; mf < 4; ++mf)
      #pragma unroll
      for (int nf = 0; nf < 2; ++nf)
        acc[mf][nf] = (f32x4){0.f,0.f,0.f,0.f};
    #pragma unroll
    for (int ks = 0; ks < 4; ++ks)
      #pragma unroll
      for (int mf = 0; mf < 4; ++mf) {
        const f16x8 A = *(f16x8*)&m1l[(mf*16 + lr)*136 + ks*32 + lg*8];
        acc[mf][0] = __builtin_amdgcn_mfma_f32_16x16x32_f16(A, W2f[ks][0], acc[mf][0], 0, 0, 0);
        acc[mf][1] = __builtin_amdgcn_mfma_f32_16x16x32_f16(A, W2f[ks][1], acc[mf][1], 0, 0, 0);
      }
    __syncthreads();  // m1 reads done; clobber with Mlds
    #pragma unroll
    for (int mf = 0; mf < 4; ++mf)
      #pragma unroll
      for (int nf = 0; nf < 2; ++nf)
        #pragma unroll
        for (int j = 0; j < 4; ++j)
          Mlds[(mf*16 + lg*4 + j)*132 + (w*32 + nf*16 + lr)] = acc[mf][nf][j] + b2v[nf];
    __syncthreads();
    // ---- segmented reduce by sorted dst -> agg ----
    {
      const int c = t & 127, hf = t >> 7;
      float run = 0.f;
      for (int r = hf*32; r < hf*32 + 32; ++r) {
        run += Mlds[r*132 + c];
        if (r == hf*32 + 31 || sdst[r] != sdst[r+1]) {
          atomicAdd(&agg[(size_t)sdst[r]*128 + c], run);
          run = 0.f;
        }
      }
    }
  }
  // ---- g_vec partials ----
  __syncthreads();
  if (q == 0) { vred[le*3] = vxa; vred[le*3+1] = vya; vred[le*3+2] = vza; }
  __syncthreads();
  if (t < 3) {
    float s = 0.f;
    for (int i = 0; i < 64; ++i) s += vred[i*3 + t];
    atomicAdd(&gvsum[t], s);
  }
}

// ---------------- Kernel C: update MLP + LayerNorm + g_P partials ----------------
__global__ __launch_bounds__(256) void k_upd(
    const float* h /*aliases hn*/, const float* __restrict__ agg,
    const float* __restrict__ U1, const float* __restrict__ u1,
    const float* __restrict__ U2, const float* __restrict__ u2,
    const float* __restrict__ lg, const float* __restrict__ lb,
    float* hn, float* __restrict__ gsum) {
  __shared__ __align__(16) float U1l[256*128];
  __shared__ __align__(16) float xl[16*256];
  __shared__ __align__(16) float t1l[16*128];
  __shared__ __align__(16) float cred[4*128];
  const int t = threadIdx.x;
  for (int i = t*4; i < 256*128; i += 1024)
    *(float4*)&U1l[i] = *(const float4*)&U1[i];
  const int c0 = (t&31)*4, rg = t>>5;
  const float4 u1v = *(const float4*)&u1[c0];
  const float4 u2v = *(const float4*)&u2[c0];
  const float4 gv4 = *(const float4*)&lg[c0];
  const float4 bv4 = *(const float4*)&lb[c0];
  float pc0=0, pc1=0, pc2=0, pc3=0;
  for (int tile = blockIdx.x; tile < NN/16; tile += gridDim.x) {
    const int r0 = tile*16;
    __syncthreads();
    for (int i = t*4; i < 16*256; i += 1024) {
      const int r = i >> 8, k = i & 255;
      const float4 v = (k < 128)
          ? *(const float4*)&h  [((size_t)r0+r)*128 + k]
          : *(const float4*)&agg[((size_t)r0+r)*128 + (k-128)];
      *(float4*)&xl[i] = v;
    }
    __syncthreads();
    float a0x=0,a0y=0,a0z=0,a0w=0,a1x=0,a1y=0,a1z=0,a1w=0;
    #pragma unroll 2
    for (int k = 0; k < 256; ++k) {
      const float4 w = *(float4*)&U1l[k*128 + c0];
      const float x0 = xl[(rg*2)*256 + k];
      const float x1 = xl[(rg*2+1)*256 + k];
      a0x+=x0*w.x; a0y+=x0*w.y; a0z+=x0*w.z; a0w+=x0*w.w;
      a1x+=x1*w.x; a1y+=x1*w.y; a1z+=x1*w.z; a1w+=x1*w.w;
    }
    *(float4*)&t1l[(rg*2)*128 + c0] = make_float4(
        siluf(a0x+u1v.x), siluf(a0y+u1v.y), siluf(a0z+u1v.z), siluf(a0w+u1v.w));
    *(float4*)&t1l[(rg*2+1)*128 + c0] = make_float4(
        siluf(a1x+u1v.x), siluf(a1y+u1v.y), siluf(a1z+u1v.z), siluf(a1w+u1v.w));
    __syncthreads();
    float b0x=0,b0y=0,b0z=0,b0w=0,b1x=0,b1y=0,b1z=0,b1w=0;
    #pragma unroll 2
    for (int k = 0; k < 128; ++k) {
      const float4 w = *(const float4*)&U2[k*128 + c0];
      const float x0 = t1l[(rg*2)*128 + k];
      const float x1 = t1l[(rg*2+1)*128 + k];
      b0x+=x0*w.x; b0y+=x0*w.y; b0z+=x0*w.z; b0w+=x0*w.w;
      b1x+=x1*w.x; b1y+=x1*w.y; b1z+=x1*w.z; b1w+=x1*w.w;
    }
    const float v00=b0x+u2v.x, v01=b0y+u2v.y, v02=b0z+u2v.z, v03=b0w+u2v.w;
    const float v10=b1x+u2v.x, v11=b1y+u2v.y, v12=b1z+u2v.z, v13=b1w+u2v.w;
    float s0 = v00+v01+v02+v03, q0 = v00*v00+v01*v01+v02*v02+v03*v03;
    float s1 = v10+v11+v12+v13, q1 = v10*v10+v11*v11+v12*v12+v13*v13;
    #pragma unroll
    for (int m = 16; m > 0; m >>= 1) {
      s0 += __shfl_xor(s0,m,32); q0 += __shfl_xor(q0,m,32);
      s1 += __shfl_xor(s1,m,32); q1 += __shfl_xor(q1,m,32);
    }
    const float mu0 = s0*(1.f/128.f), var0 = q0*(1.f/128.f)-mu0*mu0;
    const float mu1 = s1*(1.f/128.f), var1 = q1*(1.f/128.f)-mu1*mu1;
    const float rs0 = rsqrtf(var0+1e-5f), rs1 = rsqrtf(var1+1e-5f);
    const float h00=(v00-mu0)*rs0*gv4.x+bv4.x, h01=(v01-mu0)*rs0*gv4.y+bv4.y;
    const float h02=(v02-mu0)*rs0*gv4.z+bv4.z, h03=(v03-mu0)*rs0*gv4.w+bv4.w;
    const float h10=(v10-mu1)*rs1*gv4.x+bv4.x, h11=(v11-mu1)*rs1*gv4.y+bv4.y;
    const float h12=(v12-mu1)*rs1*gv4.z+bv4.z, h13=(v13-mu1)*rs1*gv4.w+bv4.w;
    *(float4*)&hn[((size_t)r0+rg*2)*128 + c0]   = make_float4(h00,h01,h02,h03);
    *(float4*)&hn[((size_t)r0+rg*2+1)*128 + c0] = make_float4(h10,h11,h12,h13);
    pc0 += h00+h10; pc1 += h01+h11; pc2 += h02+h12; pc3 += h03+h13;
  }
  pc0 += __shfl_xor(pc0, 32, 64);
  pc1 += __shfl_xor(pc1, 32, 64);
  pc2 += __shfl_xor(pc2, 32, 64);
  pc3 += __shfl_xor(pc3, 32, 64);
  __syncthreads();
  if ((t & 32) == 0) {
    const int w = t >> 6;
    cred[w*128 + c0+0] = pc0; cred[w*128 + c0+1] = pc1;
    cred[w*128 + c0+2] = pc2; cred[w*128 + c0+3] = pc3;
  }
  __syncthreads();
  if (t < 128) {
    const float s = cred[t] + cred[128+t] + cred[256+t] + cred[384+t];
    atomicAdd(&gsum[t], s);
  }
}

// ---------------- Kernel D: finalize g_P, g_vec ----------------
__global__ void k_fin(const float* __restrict__ gsum, const float* __restrict__ gvsum,
                      float* __restrict__ gp, float* __restrict__ gvo) {
  const int t = threadIdx.x;
  if (t < 128) gp[t] = gsum[t] * (1.0f/NN);
  if (t == 0) {
    const float x = gvsum[0]*(1.0f/NN);
    const float y = gvsum[1]*(1.0f/NN);
    const float z = gvsum[2]*(1.0f/NN);
    const float n = sqrtf(x*x+y*y+z*z) + 1e-8f;
    gvo[0]=x/n; gvo[1]=y/n; gvo[2]=z/n;
  }
}

extern "C" void kernel_launch(void* const* d_in, const int* in_sizes, int n_in,
                              void* d_out, int out_size, void* d_ws, size_t ws_size,
                              hipStream_t stream) {
  const float* nf  = (const float*)d_in[0];
  const float* pos = (const float*)d_in[1];
  const int*   ei  = (const int*)d_in[2];
  const float* Wi  = (const float*)d_in[3];
  const float* bi  = (const float*)d_in[4];
  const float* W1  = (const float*)d_in[5];
  const float* b1  = (const float*)d_in[6];
  const float* W2  = (const float*)d_in[7];
  const float* b2  = (const float*)d_in[8];
  const float* U1  = (const float*)d_in[9];
  const float* u1  = (const float*)d_in[10];
  const float* U2  = (const float*)d_in[11];
  const float* u2  = (const float*)d_in[12];
  const float* lg  = (const float*)d_in[13];
  const float* lb  = (const float*)d_in[14];

  float* out = (float*)d_out;
  float* h   = out;                          // h lives in d_out, overwritten by hn
  float* gp  = out + (size_t)NN*HH;
  float* gv  = gp + HH;

  // ---- workspace layout (4B units) ----
  int*   cnt   = (int*)d_ws;                       // [50176]
  float* gsum  = (float*)d_ws + 50176;             // [128]
  float* gvsum = (float*)d_ws + 50304;             // [4]
  float* agg   = (float*)d_ws + 50432;             // [6,400,000]  (16B-aligned)
  int*   off   = (int*)d_ws + 6450432;             // [50176]
  int*   cur   = (int*)d_ws + 6500608;             // [50176]
  int*   sSrc  = (int*)d_ws + 6550784;             // [800000]
  int*   sDst  = (int*)d_ws + 7350784;             // [800000]
  float* hsum  = (float*)d_ws + 8150784;           // [50000]  -> total ~32.8 MB

  // zero cnt + gsum + gvsum + agg in one shot
  hipMemsetAsync(d_ws, 0, (size_t)(50432 + 6400000) * sizeof(float), stream);

  k_linin  <<<1024, 256,  0, stream>>>(nf, Wi, bi, h, hsum);
  k_count  <<<3125, 256,  0, stream>>>(ei, cnt);
  k_scan   <<<1,    1024, 0, stream>>>(cnt, off, cur);
  k_scatter<<<3125, 256,  0, stream>>>(ei, cur, sSrc, sDst);
  k_edge   <<<1024, 256,  0, stream>>>(sSrc, sDst, pos, h, hsum,
                                       W1, b1, W2, b2, agg, gvsum);
  k_upd    <<<512,  256,  0, stream>>>(h, agg, U1, u1, U2, u2, lg, lb, out, gsum);
  k_fin    <<<1,    128,  0, stream>>>(gsum, gvsum, gp, gv);
}

// Round 3
// 479.531 us; speedup vs baseline: 5.6164x; 1.5048x over previous
//
#include <hip/hip_runtime.h>
#include <math.h>

#define NN 50000
#define EE 800000
#define HH 128

typedef _Float16 f16;
typedef _Float16 f16x4 __attribute__((ext_vector_type(4)));
typedef _Float16 f16x8 __attribute__((ext_vector_type(8)));
typedef float f32x4 __attribute__((ext_vector_type(4)));

__device__ __forceinline__ float sigf(float x)  { return 1.0f/(1.0f+__expf(-x)); }
__device__ __forceinline__ float siluf(float x) { return x/(1.0f+__expf(-x)); }

// ---------------- Kernel A: h = nf @ Wi + bi (f16 MFMA) ; hsum = rowsum(h) ----------------
// 256 thr = 4 waves, each wave owns 32 output cols. Tile = 64 nodes.
__global__ __launch_bounds__(256) void k_linin(
    const float* __restrict__ nf, const float* __restrict__ Wi,
    const float* __restrict__ bi, float* __restrict__ h, float* __restrict__ hsum) {
  __shared__ __align__(16) f16   Xl[64*136];   // 17408 B
  __shared__ __align__(16) float Hl[64*132];   // 33792 B
  const int t = threadIdx.x;
  const int w = t >> 6, l = t & 63;
  const int lr = l & 15, lg = l >> 4;

  f16x8 Wf[4][2];
  #pragma unroll
  for (int ks = 0; ks < 4; ++ks)
    #pragma unroll
    for (int nn = 0; nn < 2; ++nn) {
      f16x8 v;
      #pragma unroll
      for (int j = 0; j < 8; ++j)
        v[j] = (f16)Wi[(ks*32 + lg*8 + j)*128 + (w*32 + nn*16 + lr)];
      Wf[ks][nn] = v;
    }
  float biv[2];
  #pragma unroll
  for (int nn = 0; nn < 2; ++nn) biv[nn] = bi[w*32 + nn*16 + lr];

  for (int tile = blockIdx.x; tile < (NN+63)/64; tile += gridDim.x) {
    const int r0 = tile*64;
    __syncthreads();
    // stage nf -> f16 LDS
    #pragma unroll
    for (int i = 0; i < 4; ++i) {
      const int ch = t + i*256;
      const int r = ch >> 4, co = (ch & 15)*8;
      const int gr = r0 + r;
      f16x8 v;
      if (gr < NN) {
        const float4 a = *(const float4*)&nf[(size_t)gr*128 + co];
        const float4 b = *(const float4*)&nf[(size_t)gr*128 + co + 4];
        v[0]=(f16)a.x; v[1]=(f16)a.y; v[2]=(f16)a.z; v[3]=(f16)a.w;
        v[4]=(f16)b.x; v[5]=(f16)b.y; v[6]=(f16)b.z; v[7]=(f16)b.w;
      } else {
        #pragma unroll
        for (int j = 0; j < 8; ++j) v[j] = (f16)0.f;
      }
      *(f16x8*)&Xl[r*136 + co] = v;
    }
    __syncthreads();
    f32x4 acc[4][2];
    #pragma unroll
    for (int mf = 0; mf < 4; ++mf)
      #pragma unroll
      for (int nn = 0; nn < 2; ++nn) acc[mf][nn] = (f32x4){0.f,0.f,0.f,0.f};
    #pragma unroll
    for (int ks = 0; ks < 4; ++ks)
      #pragma unroll
      for (int mf = 0; mf < 4; ++mf) {
        const f16x8 A = *(f16x8*)&Xl[(mf*16 + lr)*136 + ks*32 + lg*8];
        acc[mf][0] = __builtin_amdgcn_mfma_f32_16x16x32_f16(A, Wf[ks][0], acc[mf][0], 0, 0, 0);
        acc[mf][1] = __builtin_amdgcn_mfma_f32_16x16x32_f16(A, Wf[ks][1], acc[mf][1], 0, 0, 0);
      }
    #pragma unroll
    for (int mf = 0; mf < 4; ++mf)
      #pragma unroll
      for (int nn = 0; nn < 2; ++nn)
        #pragma unroll
        for (int j = 0; j < 4; ++j)
          Hl[(mf*16 + lg*4 + j)*132 + (w*32 + nn*16 + lr)] = acc[mf][nn][j] + biv[nn];
    __syncthreads();
    // coalesced write-out of h
    #pragma unroll
    for (int i = 0; i < 8; ++i) {
      const int ch = t + i*256;
      const int r = ch >> 5, co = (ch & 31)*4;
      const int gr = r0 + r;
      if (gr < NN)
        *(float4*)&h[(size_t)gr*128 + co] = *(float4*)&Hl[r*132 + co];
    }
    // hsum: 4 threads per row
    {
      const int r = t >> 2, q = t & 3;
      const int gr = r0 + r;
      float s = 0.f;
      #pragma unroll
      for (int j = 0; j < 8; ++j) {
        const float4 v = *(float4*)&Hl[r*132 + q*32 + j*4];
        s += v.x + v.y + v.z + v.w;
      }
      s += __shfl_xor(s, 1, 4);
      s += __shfl_xor(s, 2, 4);
      if (q == 0 && gr < NN) hsum[gr] = s;
    }
  }
}

// ---------------- Sort kernels: count / scan / scatter ----------------
__global__ void k_count(const int* __restrict__ ei, int* __restrict__ cnt) {
  const int e = blockIdx.x*256 + threadIdx.x;
  if (e < EE) atomicAdd(&cnt[ei[EE+e]], 1);
}

__global__ __launch_bounds__(1024) void k_scan(const int* __restrict__ cnt,
                                               int* __restrict__ off, int* __restrict__ cur) {
  __shared__ int part[1024];
  const int t = threadIdx.x;
  const int CH = 49;
  const int base = t*CH;
  int s = 0;
  for (int i = 0; i < CH; ++i) {
    const int idx = base+i;
    s += (idx < NN) ? cnt[idx] : 0;
  }
  part[t] = s;
  __syncthreads();
  for (int d = 1; d < 1024; d <<= 1) {
    int u = (t >= d) ? part[t-d] : 0;
    __syncthreads();
    part[t] += u;
    __syncthreads();
  }
  int run = part[t] - s;
  for (int i = 0; i < CH; ++i) {
    const int idx = base+i;
    if (idx < NN) { off[idx] = run; cur[idx] = run; run += cnt[idx]; }
  }
}

__global__ void k_scatter(const int* __restrict__ ei, int* __restrict__ cur,
                          int* __restrict__ sSrc, int* __restrict__ sDst) {
  const int e = blockIdx.x*256 + threadIdx.x;
  if (e < EE) {
    const int d = ei[EE+e];
    const int p = atomicAdd(&cur[d], 1);
    sSrc[p] = ei[e];
    sDst[p] = d;
  }
}

// ---------------- Kernel B: MFMA edge MLP + segmented scatter ----------------
__global__ __launch_bounds__(256) void k_edge(
    const int* __restrict__ sSrc, const int* __restrict__ sDst,
    const float* __restrict__ pos, const float* __restrict__ h,
    const float* __restrict__ hsum,
    const float* __restrict__ W1, const float* __restrict__ b1,
    const float* __restrict__ W2, const float* __restrict__ b2,
    float* __restrict__ agg, float* __restrict__ gvsum) {
  __shared__ __align__(16) unsigned char smem[64*168*2 + 64*136*2];
  __shared__ int   sdst[64];
  __shared__ float vred[64*3];
  f16*   xl   = (f16*)smem;                    // [64][168] (row uses [0,160))
  f16*   m1l  = (f16*)(smem + 64*168*2);       // [64][136] (row uses [0,128))
  float* Mlds = (float*)smem;                  // [64][132] overlay

  const int t = threadIdx.x;
  const int w = t >> 6, l = t & 63;
  const int lr = l & 15;
  const int lg = l >> 4;
  const int le = t >> 2, q = t & 3;

  f16x8 W1f[5][2], W2f[4][2];
  #pragma unroll
  for (int ks = 0; ks < 5; ++ks)
    #pragma unroll
    for (int nn = 0; nn < 2; ++nn) {
      f16x8 v;
      #pragma unroll
      for (int j = 0; j < 8; ++j) {
        const int k = ks*32 + lg*8 + j;
        const int c = w*32 + nn*16 + lr;
        v[j] = (k < 136) ? (f16)W1[k*128 + c] : (f16)0.f;
      }
      W1f[ks][nn] = v;
    }
  #pragma unroll
  for (int ks = 0; ks < 4; ++ks)
    #pragma unroll
    for (int nn = 0; nn < 2; ++nn) {
      f16x8 v;
      #pragma unroll
      for (int j = 0; j < 8; ++j) {
        const int k = ks*32 + lg*8 + j;
        const int c = w*32 + nn*16 + lr;
        v[j] = (f16)W2[k*128 + c];
      }
      W2f[ks][nn] = v;
    }
  float b1v[2], b2v[2];
  #pragma unroll
  for (int nn = 0; nn < 2; ++nn) {
    b1v[nn] = b1[w*32 + nn*16 + lr];
    b2v[nn] = b2[w*32 + nn*16 + lr];
  }

  float vxa = 0.f, vya = 0.f, vza = 0.f;

  for (int tile = blockIdx.x; tile < EE/64; tile += gridDim.x) {
    const int e0 = tile*64;
    __syncthreads();
    {
      const int s = sSrc[e0 + le];
      #pragma unroll
      for (int i = 0; i < 8; ++i) {
        const float4 v4 = *(const float4*)&h[(size_t)s*128 + q*32 + i*4];
        f16x4 o = { (f16)v4.x, (f16)v4.y, (f16)v4.z, (f16)v4.w };
        *(f16x4*)&xl[le*168 + q*32 + i*4] = o;
      }
      if (q == 0) {
        const int d = sDst[e0 + le];
        sdst[le] = d;
        const float rx = pos[d*3+0]-pos[s*3+0];
        const float ry = pos[d*3+1]-pos[s*3+1];
        const float rz = pos[d*3+2]-pos[s*3+2];
        const float dij = sqrtf(rx*rx+ry*ry+rz*rz);
        const float inv = 1.0f/(dij + 1e-8f);
        const float g = sigf(hsum[s]);
        vxa += g*rx*inv; vya += g*ry*inv; vza += g*rz*inv;
        #pragma unroll
        for (int qq = 0; qq < 8; ++qq) {
          const float dc = dij - (float)qq * (8.0f/7.0f);
          xl[le*168 + 128 + qq] = (f16)__expf(-0.5f*dc*dc);
        }
        f16x8 z;
        #pragma unroll
        for (int j = 0; j < 8; ++j) z[j] = (f16)0.f;
        *(f16x8*)&xl[le*168 + 136] = z;
        *(f16x8*)&xl[le*168 + 144] = z;
        *(f16x8*)&xl[le*168 + 152] = z;
      }
    }
    __syncthreads();
    f32x4 acc[4][2];
    #pragma unroll
    for (int mf = 0; mf < 4; ++mf)
      #pragma unroll
      for (int nn = 0; nn < 2; ++nn)
        acc[mf][nn] = (f32x4){0.f,0.f,0.f,0.f};
    #pragma unroll
    for (int ks = 0; ks < 5; ++ks)
      #pragma unroll
      for (int mf = 0; mf < 4; ++mf) {
        const f16x8 A = *(f16x8*)&xl[(mf*16 + lr)*168 + ks*32 + lg*8];
        acc[mf][0] = __builtin_amdgcn_mfma_f32_16x16x32_f16(A, W1f[ks][0], acc[mf][0], 0, 0, 0);
        acc[mf][1] = __builtin_amdgcn_mfma_f32_16x16x32_f16(A, W1f[ks][1], acc[mf][1], 0, 0, 0);
      }
    #pragma unroll
    for (int mf = 0; mf < 4; ++mf)
      #pragma unroll
      for (int nn = 0; nn < 2; ++nn)
        #pragma unroll
        for (int j = 0; j < 4; ++j) {
          const float v = siluf(acc[mf][nn][j] + b1v[nn]);
          m1l[(mf*16 + lg*4 + j)*136 + (w*32 + nn*16 + lr)] = (f16)v;
        }
    __syncthreads();
    #pragma unroll
    for (int mf = 0; mf < 4; ++mf)
      #pragma unroll
      for (int nn = 0; nn < 2; ++nn)
        acc[mf][nn] = (f32x4){0.f,0.f,0.f,0.f};
    #pragma unroll
    for (int ks = 0; ks < 4; ++ks)
      #pragma unroll
      for (int mf = 0; mf < 4; ++mf) {
        const f16x8 A = *(f16x8*)&m1l[(mf*16 + lr)*136 + ks*32 + lg*8];
        acc[mf][0] = __builtin_amdgcn_mfma_f32_16x16x32_f16(A, W2f[ks][0], acc[mf][0], 0, 0, 0);
        acc[mf][1] = __builtin_amdgcn_mfma_f32_16x16x32_f16(A, W2f[ks][1], acc[mf][1], 0, 0, 0);
      }
    __syncthreads();
    #pragma unroll
    for (int mf = 0; mf < 4; ++mf)
      #pragma unroll
      for (int nn = 0; nn < 2; ++nn)
        #pragma unroll
        for (int j = 0; j < 4; ++j)
          Mlds[(mf*16 + lg*4 + j)*132 + (w*32 + nn*16 + lr)] = acc[mf][nn][j] + b2v[nn];
    __syncthreads();
    {
      const int c = t & 127, hf = t >> 7;
      float run = 0.f;
      for (int r = hf*32; r < hf*32 + 32; ++r) {
        run += Mlds[r*132 + c];
        if (r == hf*32 + 31 || sdst[r] != sdst[r+1]) {
          atomicAdd(&agg[(size_t)sdst[r]*128 + c], run);
          run = 0.f;
        }
      }
    }
  }
  __syncthreads();
  if (q == 0) { vred[le*3] = vxa; vred[le*3+1] = vya; vred[le*3+2] = vza; }
  __syncthreads();
  if (t < 3) {
    float s = 0.f;
    for (int i = 0; i < 64; ++i) s += vred[i*3 + t];
    atomicAdd(&gvsum[t], s);
  }
}

// ---------------- Kernel C: update MLP (f16 MFMA) + LayerNorm + g_P ----------------
// Tile = 64 nodes. X = [h | agg] -> f16 [64][264]. U1,U2 frags in registers.
__global__ __launch_bounds__(256) void k_upd(
    const float* __restrict__ h, const float* __restrict__ agg,
    const float* __restrict__ U1, const float* __restrict__ u1,
    const float* __restrict__ U2, const float* __restrict__ u2,
    const float* __restrict__ lgm, const float* __restrict__ lbt,
    float* __restrict__ hn, float* __restrict__ gsum) {
  __shared__ __align__(16) f16   Xl[64*264];    // 33792 B (overlay: HUl float[64][132])
  __shared__ __align__(16) f16   t1l[64*136];   // 17408 B
  __shared__ __align__(16) float cred[4*128];
  float* HUl = (float*)Xl;

  const int t = threadIdx.x;
  const int w = t >> 6, l = t & 63;
  const int lr = l & 15, lg = l >> 4;

  f16x8 U1f[8][2], U2f[4][2];
  #pragma unroll
  for (int ks = 0; ks < 8; ++ks)
    #pragma unroll
    for (int nn = 0; nn < 2; ++nn) {
      f16x8 v;
      #pragma unroll
      for (int j = 0; j < 8; ++j)
        v[j] = (f16)U1[(ks*32 + lg*8 + j)*128 + (w*32 + nn*16 + lr)];
      U1f[ks][nn] = v;
    }
  #pragma unroll
  for (int ks = 0; ks < 4; ++ks)
    #pragma unroll
    for (int nn = 0; nn < 2; ++nn) {
      f16x8 v;
      #pragma unroll
      for (int j = 0; j < 8; ++j)
        v[j] = (f16)U2[(ks*32 + lg*8 + j)*128 + (w*32 + nn*16 + lr)];
      U2f[ks][nn] = v;
    }
  float u1v[2], u2v[2];
  #pragma unroll
  for (int nn = 0; nn < 2; ++nn) {
    u1v[nn] = u1[w*32 + nn*16 + lr];
    u2v[nn] = u2[w*32 + nn*16 + lr];
  }
  const int c0 = (t & 31)*4;
  const float4 gv4 = *(const float4*)&lgm[c0];
  const float4 bv4 = *(const float4*)&lbt[c0];
  float pc0=0, pc1=0, pc2=0, pc3=0;

  for (int tile = blockIdx.x; tile < (NN+63)/64; tile += gridDim.x) {
    const int r0 = tile*64;
    __syncthreads();
    // stage [h | agg] -> f16
    #pragma unroll
    for (int i = 0; i < 8; ++i) {
      const int ch = t + i*256;
      const int r = ch >> 5, co = (ch & 31)*8;
      const int gr = r0 + r;
      f16x8 v;
      if (gr < NN) {
        const float* srcp = (co < 128) ? &h[(size_t)gr*128 + co]
                                       : &agg[(size_t)gr*128 + (co-128)];
        const float4 a = *(const float4*)srcp;
        const float4 b = *(const float4*)(srcp + 4);
        v[0]=(f16)a.x; v[1]=(f16)a.y; v[2]=(f16)a.z; v[3]=(f16)a.w;
        v[4]=(f16)b.x; v[5]=(f16)b.y; v[6]=(f16)b.z; v[7]=(f16)b.w;
      } else {
        #pragma unroll
        for (int j = 0; j < 8; ++j) v[j] = (f16)0.f;
      }
      *(f16x8*)&Xl[r*264 + co] = v;
    }
    __syncthreads();
    // GEMM1: K=256
    f32x4 acc[4][2];
    #pragma unroll
    for (int mf = 0; mf < 4; ++mf)
      #pragma unroll
      for (int nn = 0; nn < 2; ++nn) acc[mf][nn] = (f32x4){0.f,0.f,0.f,0.f};
    #pragma unroll
    for (int ks = 0; ks < 8; ++ks)
      #pragma unroll
      for (int mf = 0; mf < 4; ++mf) {
        const f16x8 A = *(f16x8*)&Xl[(mf*16 + lr)*264 + ks*32 + lg*8];
        acc[mf][0] = __builtin_amdgcn_mfma_f32_16x16x32_f16(A, U1f[ks][0], acc[mf][0], 0, 0, 0);
        acc[mf][1] = __builtin_amdgcn_mfma_f32_16x16x32_f16(A, U1f[ks][1], acc[mf][1], 0, 0, 0);
      }
    #pragma unroll
    for (int mf = 0; mf < 4; ++mf)
      #pragma unroll
      for (int nn = 0; nn < 2; ++nn)
        #pragma unroll
        for (int j = 0; j < 4; ++j) {
          const float v = siluf(acc[mf][nn][j] + u1v[nn]);
          t1l[(mf*16 + lg*4 + j)*136 + (w*32 + nn*16 + lr)] = (f16)v;
        }
    __syncthreads();
    // GEMM2: K=128
    #pragma unroll
    for (int mf = 0; mf < 4; ++mf)
      #pragma unroll
      for (int nn = 0; nn < 2; ++nn) acc[mf][nn] = (f32x4){0.f,0.f,0.f,0.f};
    #pragma unroll
    for (int ks = 0; ks < 4; ++ks)
      #pragma unroll
      for (int mf = 0; mf < 4; ++mf) {
        const f16x8 A = *(f16x8*)&t1l[(mf*16 + lr)*136 + ks*32 + lg*8];
        acc[mf][0] = __builtin_amdgcn_mfma_f32_16x16x32_f16(A, U2f[ks][0], acc[mf][0], 0, 0, 0);
        acc[mf][1] = __builtin_amdgcn_mfma_f32_16x16x32_f16(A, U2f[ks][1], acc[mf][1], 0, 0, 0);
      }
    // hu -> LDS (Xl is dead after GEMM1+t1l-sync)
    #pragma unroll
    for (int mf = 0; mf < 4; ++mf)
      #pragma unroll
      for (int nn = 0; nn < 2; ++nn)
        #pragma unroll
        for (int j = 0; j < 4; ++j)
          HUl[(mf*16 + lg*4 + j)*132 + (w*32 + nn*16 + lr)] = acc[mf][nn][j] + u2v[nn];
    __syncthreads();
    // LayerNorm: 8 groups of 32 lanes, 8 rows each
    {
      const int rr0 = (t >> 5)*8;
      #pragma unroll
      for (int rr = 0; rr < 8; ++rr) {
        const int r = rr0 + rr;
        const int gr = r0 + r;
        const float4 v = *(float4*)&HUl[r*132 + c0];
        float s = v.x+v.y+v.z+v.w;
        float qq = v.x*v.x+v.y*v.y+v.z*v.z+v.w*v.w;
        #pragma unroll
        for (int m = 16; m > 0; m >>= 1) {
          s  += __shfl_xor(s,  m, 32);
          qq += __shfl_xor(qq, m, 32);
        }
        const float mu = s*(1.f/128.f);
        const float var = qq*(1.f/128.f) - mu*mu;
        const float rs = rsqrtf(var + 1e-5f);
        const float o0 = (v.x-mu)*rs*gv4.x + bv4.x;
        const float o1 = (v.y-mu)*rs*gv4.y + bv4.y;
        const float o2 = (v.z-mu)*rs*gv4.z + bv4.z;
        const float o3 = (v.w-mu)*rs*gv4.w + bv4.w;
        if (gr < NN) {
          *(float4*)&hn[(size_t)gr*128 + c0] = make_float4(o0,o1,o2,o3);
          pc0 += o0; pc1 += o1; pc2 += o2; pc3 += o3;
        }
      }
    }
  }
  // g_P column partials -> gsum
  pc0 += __shfl_xor(pc0, 32, 64);
  pc1 += __shfl_xor(pc1, 32, 64);
  pc2 += __shfl_xor(pc2, 32, 64);
  pc3 += __shfl_xor(pc3, 32, 64);
  __syncthreads();
  if ((t & 32) == 0) {
    const int ww = t >> 6;
    cred[ww*128 + c0+0] = pc0; cred[ww*128 + c0+1] = pc1;
    cred[ww*128 + c0+2] = pc2; cred[ww*128 + c0+3] = pc3;
  }
  __syncthreads();
  if (t < 128) {
    const float s = cred[t] + cred[128+t] + cred[256+t] + cred[384+t];
    atomicAdd(&gsum[t], s);
  }
}

// ---------------- Kernel D: finalize g_P, g_vec ----------------
__global__ void k_fin(const float* __restrict__ gsum, const float* __restrict__ gvsum,
                      float* __restrict__ gp, float* __restrict__ gvo) {
  const int t = threadIdx.x;
  if (t < 128) gp[t] = gsum[t] * (1.0f/NN);
  if (t == 0) {
    const float x = gvsum[0]*(1.0f/NN);
    const float y = gvsum[1]*(1.0f/NN);
    const float z = gvsum[2]*(1.0f/NN);
    const float n = sqrtf(x*x+y*y+z*z) + 1e-8f;
    gvo[0]=x/n; gvo[1]=y/n; gvo[2]=z/n;
  }
}

extern "C" void kernel_launch(void* const* d_in, const int* in_sizes, int n_in,
                              void* d_out, int out_size, void* d_ws, size_t ws_size,
                              hipStream_t stream) {
  const float* nf  = (const float*)d_in[0];
  const float* pos = (const float*)d_in[1];
  const int*   ei  = (const int*)d_in[2];
  const float* Wi  = (const float*)d_in[3];
  const float* bi  = (const float*)d_in[4];
  const float* W1  = (const float*)d_in[5];
  const float* b1  = (const float*)d_in[6];
  const float* W2  = (const float*)d_in[7];
  const float* b2  = (const float*)d_in[8];
  const float* U1  = (const float*)d_in[9];
  const float* u1  = (const float*)d_in[10];
  const float* U2  = (const float*)d_in[11];
  const float* u2  = (const float*)d_in[12];
  const float* lg  = (const float*)d_in[13];
  const float* lb  = (const float*)d_in[14];

  float* out = (float*)d_out;
  float* h   = out;                          // h lives in d_out, overwritten by hn
  float* gp  = out + (size_t)NN*HH;
  float* gv  = gp + HH;

  // ---- workspace layout (4B units) ----
  int*   cnt   = (int*)d_ws;                       // [50176]
  float* gsum  = (float*)d_ws + 50176;             // [128]
  float* gvsum = (float*)d_ws + 50304;             // [4]
  float* agg   = (float*)d_ws + 50432;             // [6,400,000]
  int*   off   = (int*)d_ws + 6450432;             // [50176]
  int*   cur   = (int*)d_ws + 6500608;             // [50176]
  int*   sSrc  = (int*)d_ws + 6550784;             // [800000]
  int*   sDst  = (int*)d_ws + 7350784;             // [800000]
  float* hsum  = (float*)d_ws + 8150784;           // [50000]

  hipMemsetAsync(d_ws, 0, (size_t)(50432 + 6400000) * sizeof(float), stream);

  k_linin  <<<768,  256,  0, stream>>>(nf, Wi, bi, h, hsum);
  k_count  <<<3125, 256,  0, stream>>>(ei, cnt);
  k_scan   <<<1,    1024, 0, stream>>>(cnt, off, cur);
  k_scatter<<<3125, 256,  0, stream>>>(ei, cur, sSrc, sDst);
  k_edge   <<<1024, 256,  0, stream>>>(sSrc, sDst, pos, h, hsum,
                                       W1, b1, W2, b2, agg, gvsum);
  k_upd    <<<768,  256,  0, stream>>>(h, agg, U1, u1, U2, u2, lg, lb, out, gsum);
  k_fin    <<<1,    128,  0, stream>>>(gsum, gvsum, gp, gv);
}

// Round 5
// 411.650 us; speedup vs baseline: 6.5425x; 1.1649x over previous
//
#include <hip/hip_runtime.h>
#include <math.h>

#define NN 50000
#define EE 800000
#define HH 128
#define NTILES (EE/64)

typedef _Float16 f16;
typedef _Float16 f16x4 __attribute__((ext_vector_type(4)));
typedef _Float16 f16x8 __attribute__((ext_vector_type(8)));
typedef float f32x4 __attribute__((ext_vector_type(4)));

__device__ __forceinline__ float sigf(float x)  { return 1.0f/(1.0f+__expf(-x)); }
__device__ __forceinline__ float siluf(float x) { return x/(1.0f+__expf(-x)); }

// h16 lives in-place in d_out: row gr's 128 f16 occupy the first 256 bytes of
// d_out row gr (stride 256 f16 slots). k_upd stages row gr before overwriting
// it with hn row gr (same tile, barrier-ordered), blocks own disjoint rows.

// ---------------- Kernel A: h16 = f16(nf @ Wi + bi) ; hsum = rowsum ----------------
__global__ __launch_bounds__(256) void k_linin(
    const float* __restrict__ nf, const float* __restrict__ Wi,
    const float* __restrict__ bi, f16* __restrict__ h16, float* __restrict__ hsum) {
  __shared__ __align__(16) f16   Xl[64*136];
  __shared__ __align__(16) float Hl[64*132];
  const int t = threadIdx.x;
  const int w = t >> 6, l = t & 63;
  const int lr = l & 15, lg = l >> 4;

  f16x8 Wf[4][2];
  #pragma unroll
  for (int ks = 0; ks < 4; ++ks)
    #pragma unroll
    for (int nn = 0; nn < 2; ++nn) {
      f16x8 v;
      #pragma unroll
      for (int j = 0; j < 8; ++j)
        v[j] = (f16)Wi[(ks*32 + lg*8 + j)*128 + (w*32 + nn*16 + lr)];
      Wf[ks][nn] = v;
    }
  float biv[2];
  #pragma unroll
  for (int nn = 0; nn < 2; ++nn) biv[nn] = bi[w*32 + nn*16 + lr];

  for (int tile = blockIdx.x; tile < (NN+63)/64; tile += gridDim.x) {
    const int r0 = tile*64;
    __syncthreads();
    #pragma unroll
    for (int i = 0; i < 4; ++i) {
      const int ch = t + i*256;
      const int r = ch >> 4, co = (ch & 15)*8;
      const int gr = r0 + r;
      f16x8 v;
      if (gr < NN) {
        const float4 a = *(const float4*)&nf[(size_t)gr*128 + co];
        const float4 b = *(const float4*)&nf[(size_t)gr*128 + co + 4];
        v[0]=(f16)a.x; v[1]=(f16)a.y; v[2]=(f16)a.z; v[3]=(f16)a.w;
        v[4]=(f16)b.x; v[5]=(f16)b.y; v[6]=(f16)b.z; v[7]=(f16)b.w;
      } else {
        #pragma unroll
        for (int j = 0; j < 8; ++j) v[j] = (f16)0.f;
      }
      *(f16x8*)&Xl[r*136 + co] = v;
    }
    __syncthreads();
    f32x4 acc[4][2];
    #pragma unroll
    for (int mf = 0; mf < 4; ++mf)
      #pragma unroll
      for (int nn = 0; nn < 2; ++nn) acc[mf][nn] = (f32x4){0.f,0.f,0.f,0.f};
    #pragma unroll
    for (int ks = 0; ks < 4; ++ks)
      #pragma unroll
      for (int mf = 0; mf < 4; ++mf) {
        const f16x8 A = *(f16x8*)&Xl[(mf*16 + lr)*136 + ks*32 + lg*8];
        acc[mf][0] = __builtin_amdgcn_mfma_f32_16x16x32_f16(A, Wf[ks][0], acc[mf][0], 0, 0, 0);
        acc[mf][1] = __builtin_amdgcn_mfma_f32_16x16x32_f16(A, Wf[ks][1], acc[mf][1], 0, 0, 0);
      }
    #pragma unroll
    for (int mf = 0; mf < 4; ++mf)
      #pragma unroll
      for (int nn = 0; nn < 2; ++nn)
        #pragma unroll
        for (int j = 0; j < 4; ++j)
          Hl[(mf*16 + lg*4 + j)*132 + (w*32 + nn*16 + lr)] = acc[mf][nn][j] + biv[nn];
    __syncthreads();
    // write h16 (coalesced): 64 rows x 128 f16
    #pragma unroll
    for (int i = 0; i < 4; ++i) {
      const int ch = t + i*256;
      const int r = ch >> 4, co = (ch & 15)*8;
      const int gr = r0 + r;
      if (gr < NN) {
        f16x8 v;
        const float4 a = *(float4*)&Hl[r*132 + co];
        const float4 b = *(float4*)&Hl[r*132 + co + 4];
        v[0]=(f16)a.x; v[1]=(f16)a.y; v[2]=(f16)a.z; v[3]=(f16)a.w;
        v[4]=(f16)b.x; v[5]=(f16)b.y; v[6]=(f16)b.z; v[7]=(f16)b.w;
        *(f16x8*)&h16[(size_t)gr*256 + co] = v;
      }
    }
    // hsum: 4 threads per row
    {
      const int r = t >> 2, q = t & 3;
      const int gr = r0 + r;
      float s = 0.f;
      #pragma unroll
      for (int j = 0; j < 8; ++j) {
        const float4 v = *(float4*)&Hl[r*132 + q*32 + j*4];
        s += v.x + v.y + v.z + v.w;
      }
      s += __shfl_xor(s, 1, 4);
      s += __shfl_xor(s, 2, 4);
      if (q == 0 && gr < NN) hsum[gr] = s;
    }
  }
}

// ---------------- Sort kernels ----------------
__global__ void k_count(const int* __restrict__ ei, int* __restrict__ cnt) {
  const int e = blockIdx.x*256 + threadIdx.x;
  if (e < EE) atomicAdd(&cnt[ei[EE+e]], 1);
}

__global__ __launch_bounds__(1024) void k_scan(const int* __restrict__ cnt,
                                               int* __restrict__ cur) {
  __shared__ int part[1024];
  const int t = threadIdx.x;
  const int CH = 49;
  const int base = t*CH;
  int s = 0;
  for (int i = 0; i < CH; ++i) {
    const int idx = base+i;
    s += (idx < NN) ? cnt[idx] : 0;
  }
  part[t] = s;
  __syncthreads();
  for (int d = 1; d < 1024; d <<= 1) {
    int u = (t >= d) ? part[t-d] : 0;
    __syncthreads();
    part[t] += u;
    __syncthreads();
  }
  int run = part[t] - s;
  for (int i = 0; i < CH; ++i) {
    const int idx = base+i;
    if (idx < NN) { cur[idx] = run; run += cnt[idx]; }
  }
}

__global__ void k_scatter(const int* __restrict__ ei, int* __restrict__ cur,
                          int2* __restrict__ sE) {
  const int e = blockIdx.x*256 + threadIdx.x;
  if (e < EE) {
    const int d = ei[EE+e];
    const int p = atomicAdd(&cur[d], 1);
    sE[p] = make_int2(ei[e], d);
  }
}

// ---------------- Kernel B: MFMA edge MLP + segmented scatter (prefetched) ----------------
__global__ __launch_bounds__(256) void k_edge(
    const int2* __restrict__ sE,
    const float* __restrict__ pos, const f16* __restrict__ h16,
    const float* __restrict__ hsum,
    const float* __restrict__ W1, const float* __restrict__ b1,
    const float* __restrict__ W2, const float* __restrict__ b2,
    float* __restrict__ agg, float* __restrict__ gvsum) {
  __shared__ __align__(16) unsigned char smem[64*168*2 + 64*136*2];
  __shared__ int   sdst[64];
  __shared__ float vred[64*3];
  f16*   xl   = (f16*)smem;                    // [64][168] (row uses [0,160))
  f16*   m1l  = (f16*)(smem + 64*168*2);       // [64][136] (row uses [0,128))
  float* Mlds = (float*)smem;                  // [64][132] overlay

  const int t = threadIdx.x;
  const int w = t >> 6, l = t & 63;
  const int lr = l & 15;
  const int lg = l >> 4;
  const int le = t >> 2, q = t & 3;

  f16x8 W1f[5][2], W2f[4][2];
  #pragma unroll
  for (int ks = 0; ks < 5; ++ks)
    #pragma unroll
    for (int nn = 0; nn < 2; ++nn) {
      f16x8 v;
      #pragma unroll
      for (int j = 0; j < 8; ++j) {
        const int k = ks*32 + lg*8 + j;
        const int c = w*32 + nn*16 + lr;
        v[j] = (k < 136) ? (f16)W1[k*128 + c] : (f16)0.f;
      }
      W1f[ks][nn] = v;
    }
  #pragma unroll
  for (int ks = 0; ks < 4; ++ks)
    #pragma unroll
    for (int nn = 0; nn < 2; ++nn) {
      f16x8 v;
      #pragma unroll
      for (int j = 0; j < 8; ++j) {
        const int k = ks*32 + lg*8 + j;
        const int c = w*32 + nn*16 + lr;
        v[j] = (f16)W2[k*128 + c];
      }
      W2f[ks][nn] = v;
    }
  float b1v[2], b2v[2];
  #pragma unroll
  for (int nn = 0; nn < 2; ++nn) {
    b1v[nn] = b1[w*32 + nn*16 + lr];
    b2v[nn] = b2[w*32 + nn*16 + lr];
  }

  float vxa = 0.f, vya = 0.f, vza = 0.f;

  // ---- prefetch registers ----
  f16x8 pf[4];
  int   pd_s = 0;
  float psx = 0.f, psy = 0.f, psz = 0.f, pdx = 0.f, pdy = 0.f, pdz = 0.f, phs = 0.f;

  // initial prefetch
  if (blockIdx.x < NTILES) {
    const int e0 = blockIdx.x*64;
    const int2 ed = sE[e0 + le];
    const int s = ed.x;
    pd_s = ed.y;
    #pragma unroll
    for (int i = 0; i < 4; ++i)
      pf[i] = *(const f16x8*)&h16[(size_t)s*256 + q*32 + i*8];
    if (q == 0) {
      psx = pos[s*3+0]; psy = pos[s*3+1]; psz = pos[s*3+2];
      pdx = pos[pd_s*3+0]; pdy = pos[pd_s*3+1]; pdz = pos[pd_s*3+2];
      phs = hsum[s];
    }
  }

  for (int tile = blockIdx.x; tile < NTILES; tile += gridDim.x) {
    __syncthreads();   // previous reduce done (xl/Mlds/sdst free)
    // ---- stage from prefetched regs ----
    #pragma unroll
    for (int i = 0; i < 4; ++i)
      *(f16x8*)&xl[le*168 + q*32 + i*8] = pf[i];
    if (q == 0) {
      sdst[le] = pd_s;
      const float rx = pdx - psx, ry = pdy - psy, rz = pdz - psz;
      const float dij = sqrtf(rx*rx+ry*ry+rz*rz);
      const float inv = 1.0f/(dij + 1e-8f);
      const float g = sigf(phs);
      vxa += g*rx*inv; vya += g*ry*inv; vza += g*rz*inv;
      #pragma unroll
      for (int qq = 0; qq < 8; ++qq) {
        const float dc = dij - (float)qq * (8.0f/7.0f);
        xl[le*168 + 128 + qq] = (f16)__expf(-0.5f*dc*dc);
      }
      f16x8 z;
      #pragma unroll
      for (int j = 0; j < 8; ++j) z[j] = (f16)0.f;
      *(f16x8*)&xl[le*168 + 136] = z;
      *(f16x8*)&xl[le*168 + 144] = z;
      *(f16x8*)&xl[le*168 + 152] = z;
    }
    // ---- issue prefetch for next tile (loads complete during GEMMs/reduce) ----
    {
      int tn = tile + gridDim.x;
      if (tn >= NTILES) tn = tile;   // clamp: harmless reload
      const int e0n = tn*64;
      const int2 ed = sE[e0n + le];
      const int s = ed.x;
      pd_s = ed.y;
      #pragma unroll
      for (int i = 0; i < 4; ++i)
        pf[i] = *(const f16x8*)&h16[(size_t)s*256 + q*32 + i*8];
      if (q == 0) {
        psx = pos[s*3+0]; psy = pos[s*3+1]; psz = pos[s*3+2];
        pdx = pos[pd_s*3+0]; pdy = pos[pd_s*3+1]; pdz = pos[pd_s*3+2];
        phs = hsum[s];
      }
    }
    __syncthreads();
    // ---- GEMM1: K=160 ----
    f32x4 acc[4][2];
    #pragma unroll
    for (int mf = 0; mf < 4; ++mf)
      #pragma unroll
      for (int nn = 0; nn < 2; ++nn)
        acc[mf][nn] = (f32x4){0.f,0.f,0.f,0.f};
    #pragma unroll
    for (int ks = 0; ks < 5; ++ks)
      #pragma unroll
      for (int mf = 0; mf < 4; ++mf) {
        const f16x8 A = *(f16x8*)&xl[(mf*16 + lr)*168 + ks*32 + lg*8];
        acc[mf][0] = __builtin_amdgcn_mfma_f32_16x16x32_f16(A, W1f[ks][0], acc[mf][0], 0, 0, 0);
        acc[mf][1] = __builtin_amdgcn_mfma_f32_16x16x32_f16(A, W1f[ks][1], acc[mf][1], 0, 0, 0);
      }
    #pragma unroll
    for (int mf = 0; mf < 4; ++mf)
      #pragma unroll
      for (int nn = 0; nn < 2; ++nn)
        #pragma unroll
        for (int j = 0; j < 4; ++j) {
          const float v = siluf(acc[mf][nn][j] + b1v[nn]);
          m1l[(mf*16 + lg*4 + j)*136 + (w*32 + nn*16 + lr)] = (f16)v;
        }
    __syncthreads();
    // ---- GEMM2: K=128 ----
    #pragma unroll
    for (int mf = 0; mf < 4; ++mf)
      #pragma unroll
      for (int nn = 0; nn < 2; ++nn)
        acc[mf][nn] = (f32x4){0.f,0.f,0.f,0.f};
    #pragma unroll
    for (int ks = 0; ks < 4; ++ks)
      #pragma unroll
      for (int mf = 0; mf < 4; ++mf) {
        const f16x8 A = *(f16x8*)&m1l[(mf*16 + lr)*136 + ks*32 + lg*8];
        acc[mf][0] = __builtin_amdgcn_mfma_f32_16x16x32_f16(A, W2f[ks][0], acc[mf][0], 0, 0, 0);
        acc[mf][1] = __builtin_amdgcn_mfma_f32_16x16x32_f16(A, W2f[ks][1], acc[mf][1], 0, 0, 0);
      }
    __syncthreads();   // xl/m1l reads done; clobber with Mlds
    #pragma unroll
    for (int mf = 0; mf < 4; ++mf)
      #pragma unroll
      for (int nn = 0; nn < 2; ++nn)
        #pragma unroll
        for (int j = 0; j < 4; ++j)
          Mlds[(mf*16 + lg*4 + j)*132 + (w*32 + nn*16 + lr)] = acc[mf][nn][j] + b2v[nn];
    __syncthreads();
    // ---- segmented reduce by sorted dst -> agg ----
    {
      const int c = t & 127, hf = t >> 7;
      float run = 0.f;
      for (int r = hf*32; r < hf*32 + 32; ++r) {
        run += Mlds[r*132 + c];
        if (r == hf*32 + 31 || sdst[r] != sdst[r+1]) {
          atomicAdd(&agg[(size_t)sdst[r]*128 + c], run);
          run = 0.f;
        }
      }
    }
  }
  __syncthreads();
  if (q == 0) { vred[le*3] = vxa; vred[le*3+1] = vya; vred[le*3+2] = vza; }
  __syncthreads();
  if (t < 3) {
    float s = 0.f;
    for (int i = 0; i < 64; ++i) s += vred[i*3 + t];
    atomicAdd(&gvsum[t], s);
  }
}

// ---------------- Kernel C: update MLP (f16 MFMA) + LayerNorm + g_P ----------------
__global__ __launch_bounds__(256) void k_upd(
    const f16* h16 /*aliases hn*/, const float* __restrict__ agg,
    const float* __restrict__ U1, const float* __restrict__ u1,
    const float* __restrict__ U2, const float* __restrict__ u2,
    const float* __restrict__ lgm, const float* __restrict__ lbt,
    float* hn, float* __restrict__ gsum) {
  __shared__ __align__(16) f16   Xl[64*264];
  __shared__ __align__(16) f16   t1l[64*136];
  __shared__ __align__(16) float cred[4*128];
  float* HUl = (float*)Xl;

  const int t = threadIdx.x;
  const int w = t >> 6, l = t & 63;
  const int lr = l & 15, lg = l >> 4;

  f16x8 U1f[8][2], U2f[4][2];
  #pragma unroll
  for (int ks = 0; ks < 8; ++ks)
    #pragma unroll
    for (int nn = 0; nn < 2; ++nn) {
      f16x8 v;
      #pragma unroll
      for (int j = 0; j < 8; ++j)
        v[j] = (f16)U1[(ks*32 + lg*8 + j)*128 + (w*32 + nn*16 + lr)];
      U1f[ks][nn] = v;
    }
  #pragma unroll
  for (int ks = 0; ks < 4; ++ks)
    #pragma unroll
    for (int nn = 0; nn < 2; ++nn) {
      f16x8 v;
      #pragma unroll
      for (int j = 0; j < 8; ++j)
        v[j] = (f16)U2[(ks*32 + lg*8 + j)*128 + (w*32 + nn*16 + lr)];
      U2f[ks][nn] = v;
    }
  float u1v[2], u2v[2];
  #pragma unroll
  for (int nn = 0; nn < 2; ++nn) {
    u1v[nn] = u1[w*32 + nn*16 + lr];
    u2v[nn] = u2[w*32 + nn*16 + lr];
  }
  const int c0 = (t & 31)*4;
  const float4 gv4 = *(const float4*)&lgm[c0];
  const float4 bv4 = *(const float4*)&lbt[c0];
  float pc0=0, pc1=0, pc2=0, pc3=0;

  for (int tile = blockIdx.x; tile < (NN+63)/64; tile += gridDim.x) {
    const int r0 = tile*64;
    __syncthreads();
    // stage h16 (cols 0-127, direct f16 copy)
    #pragma unroll
    for (int i = 0; i < 4; ++i) {
      const int ch = t + i*256;
      const int r = ch >> 4, co = (ch & 15)*8;
      const int gr = r0 + r;
      f16x8 v;
      if (gr < NN) {
        v = *(const f16x8*)&h16[(size_t)gr*256 + co];
      } else {
        #pragma unroll
        for (int j = 0; j < 8; ++j) v[j] = (f16)0.f;
      }
      *(f16x8*)&Xl[r*264 + co] = v;
    }
    // stage agg (cols 128-255, f32 -> f16)
    #pragma unroll
    for (int i = 0; i < 4; ++i) {
      const int ch = t + i*256;
      const int r = ch >> 4, co = (ch & 15)*8;
      const int gr = r0 + r;
      f16x8 v;
      if (gr < NN) {
        const float4 a = *(const float4*)&agg[(size_t)gr*128 + co];
        const float4 b = *(const float4*)&agg[(size_t)gr*128 + co + 4];
        v[0]=(f16)a.x; v[1]=(f16)a.y; v[2]=(f16)a.z; v[3]=(f16)a.w;
        v[4]=(f16)b.x; v[5]=(f16)b.y; v[6]=(f16)b.z; v[7]=(f16)b.w;
      } else {
        #pragma unroll
        for (int j = 0; j < 8; ++j) v[j] = (f16)0.f;
      }
      *(f16x8*)&Xl[r*264 + 128 + co] = v;
    }
    __syncthreads();
    // GEMM1: K=256
    f32x4 acc[4][2];
    #pragma unroll
    for (int mf = 0; mf < 4; ++mf)
      #pragma unroll
      for (int nn = 0; nn < 2; ++nn) acc[mf][nn] = (f32x4){0.f,0.f,0.f,0.f};
    #pragma unroll
    for (int ks = 0; ks < 8; ++ks)
      #pragma unroll
      for (int mf = 0; mf < 4; ++mf) {
        const f16x8 A = *(f16x8*)&Xl[(mf*16 + lr)*264 + ks*32 + lg*8];
        acc[mf][0] = __builtin_amdgcn_mfma_f32_16x16x32_f16(A, U1f[ks][0], acc[mf][0], 0, 0, 0);
        acc[mf][1] = __builtin_amdgcn_mfma_f32_16x16x32_f16(A, U1f[ks][1], acc[mf][1], 0, 0, 0);
      }
    #pragma unroll
    for (int mf = 0; mf < 4; ++mf)
      #pragma unroll
      for (int nn = 0; nn < 2; ++nn)
        #pragma unroll
        for (int j = 0; j < 4; ++j) {
          const float v = siluf(acc[mf][nn][j] + u1v[nn]);
          t1l[(mf*16 + lg*4 + j)*136 + (w*32 + nn*16 + lr)] = (f16)v;
        }
    __syncthreads();
    // GEMM2: K=128
    #pragma unroll
    for (int mf = 0; mf < 4; ++mf)
      #pragma unroll
      for (int nn = 0; nn < 2; ++nn) acc[mf][nn] = (f32x4){0.f,0.f,0.f,0.f};
    #pragma unroll
    for (int ks = 0; ks < 4; ++ks)
      #pragma unroll
      for (int mf = 0; mf < 4; ++mf) {
        const f16x8 A = *(f16x8*)&t1l[(mf*16 + lr)*136 + ks*32 + lg*8];
        acc[mf][0] = __builtin_amdgcn_mfma_f32_16x16x32_f16(A, U2f[ks][0], acc[mf][0], 0, 0, 0);
        acc[mf][1] = __builtin_amdgcn_mfma_f32_16x16x32_f16(A, U2f[ks][1], acc[mf][1], 0, 0, 0);
      }
    #pragma unroll
    for (int mf = 0; mf < 4; ++mf)
      #pragma unroll
      for (int nn = 0; nn < 2; ++nn)
        #pragma unroll
        for (int j = 0; j < 4; ++j)
          HUl[(mf*16 + lg*4 + j)*132 + (w*32 + nn*16 + lr)] = acc[mf][nn][j] + u2v[nn];
    __syncthreads();
    // LayerNorm
    {
      const int rr0 = (t >> 5)*8;
      #pragma unroll
      for (int rr = 0; rr < 8; ++rr) {
        const int r = rr0 + rr;
        const int gr = r0 + r;
        const float4 v = *(float4*)&HUl[r*132 + c0];
        float s = v.x+v.y+v.z+v.w;
        float qq = v.x*v.x+v.y*v.y+v.z*v.z+v.w*v.w;
        #pragma unroll
        for (int m = 16; m > 0; m >>= 1) {
          s  += __shfl_xor(s,  m, 32);
          qq += __shfl_xor(qq, m, 32);
        }
        const float mu = s*(1.f/128.f);
        const float var = qq*(1.f/128.f) - mu*mu;
        const float rs = rsqrtf(var + 1e-5f);
        const float o0 = (v.x-mu)*rs*gv4.x + bv4.x;
        const float o1 = (v.y-mu)*rs*gv4.y + bv4.y;
        const float o2 = (v.z-mu)*rs*gv4.z + bv4.z;
        const float o3 = (v.w-mu)*rs*gv4.w + bv4.w;
        if (gr < NN) {
          *(float4*)&hn[(size_t)gr*128 + c0] = make_float4(o0,o1,o2,o3);
          pc0 += o0; pc1 += o1; pc2 += o2; pc3 += o3;
        }
      }
    }
  }
  pc0 += __shfl_xor(pc0, 32, 64);
  pc1 += __shfl_xor(pc1, 32, 64);
  pc2 += __shfl_xor(pc2, 32, 64);
  pc3 += __shfl_xor(pc3, 32, 64);
  __syncthreads();
  if ((t & 32) == 0) {
    const int ww = t >> 6;
    cred[ww*128 + c0+0] = pc0; cred[ww*128 + c0+1] = pc1;
    cred[ww*128 + c0+2] = pc2; cred[ww*128 + c0+3] = pc3;
  }
  __syncthreads();
  if (t < 128) {
    const float s = cred[t] + cred[128+t] + cred[256+t] + cred[384+t];
    atomicAdd(&gsum[t], s);
  }
}

// ---------------- Kernel D: finalize ----------------
__global__ void k_fin(const float* __restrict__ gsum, const float* __restrict__ gvsum,
                      float* __restrict__ gp, float* __restrict__ gvo) {
  const int t = threadIdx.x;
  if (t < 128) gp[t] = gsum[t] * (1.0f/NN);
  if (t == 0) {
    const float x = gvsum[0]*(1.0f/NN);
    const float y = gvsum[1]*(1.0f/NN);
    const float z = gvsum[2]*(1.0f/NN);
    const float n = sqrtf(x*x+y*y+z*z) + 1e-8f;
    gvo[0]=x/n; gvo[1]=y/n; gvo[2]=z/n;
  }
}

extern "C" void kernel_launch(void* const* d_in, const int* in_sizes, int n_in,
                              void* d_out, int out_size, void* d_ws, size_t ws_size,
                              hipStream_t stream) {
  const float* nf  = (const float*)d_in[0];
  const float* pos = (const float*)d_in[1];
  const int*   ei  = (const int*)d_in[2];
  const float* Wi  = (const float*)d_in[3];
  const float* bi  = (const float*)d_in[4];
  const float* W1  = (const float*)d_in[5];
  const float* b1  = (const float*)d_in[6];
  const float* W2  = (const float*)d_in[7];
  const float* b2  = (const float*)d_in[8];
  const float* U1  = (const float*)d_in[9];
  const float* u1  = (const float*)d_in[10];
  const float* U2  = (const float*)d_in[11];
  const float* u2  = (const float*)d_in[12];
  const float* lg  = (const float*)d_in[13];
  const float* lb  = (const float*)d_in[14];

  float* out = (float*)d_out;
  f16*   h16 = (f16*)d_out;                  // h16 row gr = first 256B of out row gr
  float* gp  = out + (size_t)NN*HH;
  float* gv  = gp + HH;

  // ---- workspace layout (4B units) ----
  int*   cnt   = (int*)d_ws;                       // [50176]
  float* gsum  = (float*)d_ws + 50176;             // [128]
  float* gvsum = (float*)d_ws + 50304;             // [4] (+pad)
  float* agg   = (float*)d_ws + 50432;             // [6,400,000]
  int*   cur   = (int*)d_ws + 6450432;             // [50176]
  int2*  sE    = (int2*)((int*)d_ws + 6500608);    // [800000] int2
  float* hsum  = (float*)d_ws + 8100608;           // [50000]

  (void)hipMemsetAsync(d_ws, 0, (size_t)(50432 + 6400000) * sizeof(float), stream);

  k_linin  <<<256,  256,  0, stream>>>(nf, Wi, bi, h16, hsum);
  k_count  <<<3125, 256,  0, stream>>>(ei, cnt);
  k_scan   <<<1,    1024, 0, stream>>>(cnt, cur);
  k_scatter<<<3125, 256,  0, stream>>>(ei, cur, sE);
  k_edge   <<<1024, 256,  0, stream>>>(sE, pos, h16, hsum,
                                       W1, b1, W2, b2, agg, gvsum);
  k_upd    <<<256,  256,  0, stream>>>(h16, agg, U1, u1, U2, u2, lg, lb, out, gsum);
  k_fin    <<<1,    128,  0, stream>>>(gsum, gvsum, gp, gv);
}